// Round 9
// baseline (126.213 us; speedup 1.0000x reference)
//
#include <hip/hip_runtime.h>
#include <math.h>

// B=16384, D=1024, E=8, T=4, H=512. Output [T,B] f32.
// ws layout: [0,65536) floats  Wcomb f32 [d][64] (cols 0-31 gates t*8+e, 32-63 scores)
//            [65536,65568)     cbias[t*8+e]
//            bytes 262272+     Wfrag: 32 ksteps x {hi,lo}x{nf0..3} x 64 lanes x 8 bf16 (256 KB)

typedef float  f32x4  __attribute__((ext_vector_type(4)));
typedef short  bf16x8 __attribute__((ext_vector_type(8)));

#define WFRAG_OFF_BYTES 262272
#define SCHED_FENCE() __builtin_amdgcn_sched_barrier(0)

__device__ __forceinline__ void lds_load16(const float* g, float* l) {
  __builtin_amdgcn_global_load_lds((const __attribute__((address_space(1))) unsigned int*)g,
                                   (__attribute__((address_space(3))) unsigned int*)l, 16, 0, 0);
}

// slow-but-rare RNE split (used in precompute/swizzle only)
__device__ __forceinline__ void cvt_pair(float f0, float f1, unsigned int& hi, unsigned int& lo) {
  unsigned int u0 = __float_as_uint(f0), u1 = __float_as_uint(f1);
  unsigned int r0 = u0 + 0x7FFFu + ((u0 >> 16) & 1u);
  unsigned int r1 = u1 + 0x7FFFu + ((u1 >> 16) & 1u);
  float h0 = __uint_as_float(r0 & 0xFFFF0000u);
  float h1 = __uint_as_float(r1 & 0xFFFF0000u);
  hi = (r0 >> 16) | (r1 & 0xFFFF0000u);
  float l0 = f0 - h0, l1 = f1 - h1;
  unsigned int s0 = __float_as_uint(l0), s1 = __float_as_uint(l1);
  unsigned int q0 = s0 + 0x7FFFu + ((s0 >> 16) & 1u);
  unsigned int q1 = s1 + 0x7FFFu + ((s1 >> 16) & 1u);
  lo = (q0 >> 16) | (q1 & 0xFFFF0000u);
}

// fast in-loop split
__device__ __forceinline__ unsigned int cvtpk_bf16(float a, float b) {
  unsigned int r;
  asm("v_cvt_pk_bf16_f32 %0, %1, %2" : "=v"(r) : "v"(a), "v"(b));
  return r;
}
__device__ __forceinline__ void cvt_pair_fast(float f0, float f1, unsigned int& hi, unsigned int& lo) {
  unsigned int h = cvtpk_bf16(f0, f1);
  float h0 = __uint_as_float(h << 16);
  float h1 = __uint_as_float(h & 0xFFFF0000u);
  lo = cvtpk_bf16(f0 - h0, f1 - h1);
  hi = h;
}

// ---------------- Precompute Wcomb f32 + cbias (verified R1/R2/R5/R7/R8) ----------------
__global__ __launch_bounds__(256) void mmoe_precompute(
    const float* __restrict__ We, const float* __restrict__ be,
    const float* __restrict__ Wg, const float* __restrict__ Wt,
    float* __restrict__ ws)
{
  float* Wcomb = ws;
  float* cbias = ws + 65536;
  const int tid = threadIdx.x, lane = tid & 63, w = tid >> 6;
  const int pairid = blockIdx.x * 4 + w;
  const int e = pairid >> 10, d = pairid & 1023;

  const float* werow = We + (size_t)pairid * 512;
  float a0 = 0.f, a1 = 0.f, a2 = 0.f, a3 = 0.f;
#pragma unroll
  for (int j = 0; j < 8; ++j) {
    int h = lane + j * 64;
    float wv = werow[h];
    a0 = fmaf(wv, Wt[h],        a0);
    a1 = fmaf(wv, Wt[512 + h],  a1);
    a2 = fmaf(wv, Wt[1024 + h], a2);
    a3 = fmaf(wv, Wt[1536 + h], a3);
  }
#pragma unroll
  for (int m = 1; m < 64; m <<= 1) {
    a0 += __shfl_xor(a0, m, 64); a1 += __shfl_xor(a1, m, 64);
    a2 += __shfl_xor(a2, m, 64); a3 += __shfl_xor(a3, m, 64);
  }
  if (lane == 0) {
    Wcomb[d * 64 + 32 + 0 * 8 + e] = a0;
    Wcomb[d * 64 + 32 + 1 * 8 + e] = a1;
    Wcomb[d * 64 + 32 + 2 * 8 + e] = a2;
    Wcomb[d * 64 + 32 + 3 * 8 + e] = a3;
  }
  if (e == 0 && lane < 32) {
    int t = lane >> 3, ee = lane & 7;
    Wcomb[d * 64 + t * 8 + ee] = Wg[t * 8192 + d * 8 + ee];
  }
  if (d == 0) {
    float b0 = 0.f, b1 = 0.f, b2 = 0.f, b3 = 0.f;
#pragma unroll
    for (int j = 0; j < 8; ++j) {
      int h = lane + j * 64;
      float bv = be[e * 512 + h];
      b0 = fmaf(bv, Wt[h],        b0);
      b1 = fmaf(bv, Wt[512 + h],  b1);
      b2 = fmaf(bv, Wt[1024 + h], b2);
      b3 = fmaf(bv, Wt[1536 + h], b3);
    }
#pragma unroll
    for (int m = 1; m < 64; m <<= 1) {
      b0 += __shfl_xor(b0, m, 64); b1 += __shfl_xor(b1, m, 64);
      b2 += __shfl_xor(b2, m, 64); b3 += __shfl_xor(b3, m, 64);
    }
    if (lane == 0) {
      cbias[0 * 8 + e] = b0; cbias[1 * 8 + e] = b1;
      cbias[2 * 8 + e] = b2; cbias[3 * 8 + e] = b3;
    }
  }
}

// ---------------- Swizzle Wcomb -> bf16 hi/lo MFMA B-fragments (verified R2+) ----------------
__global__ __launch_bounds__(256) void mmoe_swizzle(const float* __restrict__ Wc,
                                                    uint4* __restrict__ wf)
{
  const int idx = blockIdx.x * 256 + threadIdx.x;  // 0..16383
  const int ks = idx >> 9;
  const int rem = idx & 511;
  const int vn = rem >> 6, l = rem & 63;
  const int v = vn >> 2, nf = vn & 3;
  const int n = nf * 16 + (l & 15);
  const int kbase = ks * 32 + (l >> 4) * 8;
  unsigned int pk[4];
#pragma unroll
  for (int p = 0; p < 4; ++p) {
    float f0 = Wc[(size_t)(kbase + 2 * p) * 64 + n];
    float f1 = Wc[(size_t)(kbase + 2 * p + 1) * 64 + n];
    unsigned int hi, lo;
    cvt_pair(f0, f1, hi, lo);
    pk[p] = v ? lo : hi;
  }
  uint4 val; val.x = pk[0]; val.y = pk[1]; val.z = pk[2]; val.w = pk[3];
  wf[idx] = val;
}

// ---------------- Main: 512 blocks x 8 waves; 32 rows/block, K-split 8 ----------------
// Wave w owns k in [w*128,(w+1)*128): 4 steps of K=32. x is staged per wave via
// global_load_lds into a private 2x4KB LDS dbuf with XOR-swizzled SOURCE addressing
// (linear LDS dest; ds_read applies the same XOR -> bank-uniform b128 reads).
// Counted vmcnt per step; WAR-safe: next stage issues only after lgkmcnt(0).
union UC { unsigned int u[4]; bf16x8 v; };

template <int S>
__device__ __forceinline__ void mmoe_step(
    const float* __restrict__ xs0, const float* __restrict__ xs1,
    const float* __restrict__ xs2, const float* __restrict__ xs3,
    float* stage0, float* stage1,
    int off00, int off01, int off10, int off11,
    const bf16x8* __restrict__ bptrw, int l,
    bf16x8 (&breg)[2][8], f32x4 (&acc)[2][4])
{
  constexpr int P = S & 1;
  // 1. wait for x(S) staged. Queue (in-order): x0 x1 B0 B1 | x2 B2 | x3 B3.
  if constexpr (S == 0) asm volatile("s_waitcnt vmcnt(20)" ::: "memory");
  if constexpr (S == 1) asm volatile("s_waitcnt vmcnt(20)" ::: "memory");
  if constexpr (S == 2) asm volatile("s_waitcnt vmcnt(20)" ::: "memory");
  if constexpr (S == 3) asm volatile("s_waitcnt vmcnt(8)"  ::: "memory");
  SCHED_FENCE();
  // 2. ds_read A-frags (swizzled offsets)
  const float* buf = P ? stage1 : stage0;
  float4 xa0 = *(const float4*)(buf + off00);
  float4 xa1 = *(const float4*)(buf + off01);
  float4 xb0 = *(const float4*)(buf + off10);
  float4 xb1 = *(const float4*)(buf + off11);
  asm volatile("s_waitcnt lgkmcnt(0)" ::: "memory");
  SCHED_FENCE();
  // 3. stage x(S+2) into same-parity buffer (safe: ds_reads completed)
  if constexpr (S + 2 < 4) {
    float* dst = P ? stage1 : stage0;
    lds_load16(xs0 + (S + 2) * 32, dst + 0 * 256);
    lds_load16(xs1 + (S + 2) * 32, dst + 1 * 256);
    lds_load16(xs2 + (S + 2) * 32, dst + 2 * 256);
    lds_load16(xs3 + (S + 2) * 32, dst + 3 * 256);
  }
  SCHED_FENCE();
  // 4. cvt + 24 MFMA (bf16x3: Ah*Bh, Ah*Bl, Al*Bh)
  UC A0h, A0l, A1h, A1l;
  cvt_pair_fast(xa0.x, xa0.y, A0h.u[0], A0l.u[0]);
  cvt_pair_fast(xa0.z, xa0.w, A0h.u[1], A0l.u[1]);
  cvt_pair_fast(xa1.x, xa1.y, A0h.u[2], A0l.u[2]);
  cvt_pair_fast(xa1.z, xa1.w, A0h.u[3], A0l.u[3]);
  cvt_pair_fast(xb0.x, xb0.y, A1h.u[0], A1l.u[0]);
  cvt_pair_fast(xb0.z, xb0.w, A1h.u[1], A1l.u[1]);
  cvt_pair_fast(xb1.x, xb1.y, A1h.u[2], A1l.u[2]);
  cvt_pair_fast(xb1.z, xb1.w, A1h.u[3], A1l.u[3]);
#pragma unroll
  for (int j = 0; j < 4; ++j)
    acc[0][j] = __builtin_amdgcn_mfma_f32_16x16x32_bf16(A0h.v, breg[P][j], acc[0][j], 0, 0, 0);
#pragma unroll
  for (int j = 0; j < 4; ++j)
    acc[1][j] = __builtin_amdgcn_mfma_f32_16x16x32_bf16(A1h.v, breg[P][j], acc[1][j], 0, 0, 0);
#pragma unroll
  for (int j = 0; j < 4; ++j)
    acc[0][j] = __builtin_amdgcn_mfma_f32_16x16x32_bf16(A0h.v, breg[P][j + 4], acc[0][j], 0, 0, 0);
#pragma unroll
  for (int j = 0; j < 4; ++j)
    acc[1][j] = __builtin_amdgcn_mfma_f32_16x16x32_bf16(A1h.v, breg[P][j + 4], acc[1][j], 0, 0, 0);
#pragma unroll
  for (int j = 0; j < 4; ++j)
    acc[0][j] = __builtin_amdgcn_mfma_f32_16x16x32_bf16(A0l.v, breg[P][j], acc[0][j], 0, 0, 0);
#pragma unroll
  for (int j = 0; j < 4; ++j)
    acc[1][j] = __builtin_amdgcn_mfma_f32_16x16x32_bf16(A1l.v, breg[P][j], acc[1][j], 0, 0, 0);
  // 5. prefetch B(S+2)
  if constexpr (S + 2 < 4) {
#pragma unroll
    for (int vn = 0; vn < 8; ++vn)
      breg[P][vn] = bptrw[(S + 2) * 512 + vn * 64 + l];
  }
  SCHED_FENCE();
}

__global__ __launch_bounds__(512, 4) void mmoe_main(
    const float* __restrict__ x,
    const float* __restrict__ bgp,   // [4][8]
    const float* __restrict__ btp,   // [4]
    const float* __restrict__ ws,
    float* __restrict__ out)
{
  __shared__ float smem[16384];      // staging [8 waves][2][1024] aliased later as cmat[8][32][64]
  const int tid = threadIdx.x;
  const int l   = tid & 63;
  const int w   = tid >> 6;          // K-eighth 0..7
  const int b0g = blockIdx.x * 32;
  const float* cbias = ws + 65536;
  const bf16x8* __restrict__ bptrw =
      (const bf16x8*)((const unsigned char*)ws + WFRAG_OFF_BYTES) + (size_t)w * 4 * 512;

  float* stage0 = smem + w * 2048;
  float* stage1 = smem + w * 2048 + 1024;

  // gll source bases: instr j covers rows j*8+(l>>3); swizzled chunk csw = (l&7)^(l>>3)
  const int rsub = l >> 3;
  const int csw  = (l & 7) ^ rsub;
  const float* xs0 = x + (size_t)(b0g + 0 * 8 + rsub) * 1024 + w * 128 + csw * 4;
  const float* xs1 = x + (size_t)(b0g + 1 * 8 + rsub) * 1024 + w * 128 + csw * 4;
  const float* xs2 = x + (size_t)(b0g + 2 * 8 + rsub) * 1024 + w * 128 + csw * 4;
  const float* xs3 = x + (size_t)(b0g + 3 * 8 + rsub) * 1024 + w * 128 + csw * 4;

  // ds_read offsets (floats): off(f,h) = ((l&15)+f*16)*32 + (((l>>4)*32 + h*16) ^ ((l&7)<<4))/4
  const int o = l >> 4;
  const int bx0 = ((o * 32 +  0) ^ ((l & 7) << 4)) >> 2;
  const int bx1 = ((o * 32 + 16) ^ ((l & 7) << 4)) >> 2;
  const int off00 = (l & 15) * 32 + bx0;
  const int off01 = (l & 15) * 32 + bx1;
  const int off10 = off00 + 512;
  const int off11 = off01 + 512;

  bf16x8 breg[2][8];
  f32x4  acc[2][4];
#pragma unroll
  for (int f = 0; f < 2; ++f)
#pragma unroll
    for (int nf = 0; nf < 4; ++nf) acc[f][nf] = (f32x4){0.f, 0.f, 0.f, 0.f};

  // prologue: stage x(0)->buf0, x(1)->buf1; prefetch B(0),B(1)
  lds_load16(xs0 + 0,  stage0 + 0 * 256);
  lds_load16(xs1 + 0,  stage0 + 1 * 256);
  lds_load16(xs2 + 0,  stage0 + 2 * 256);
  lds_load16(xs3 + 0,  stage0 + 3 * 256);
  lds_load16(xs0 + 32, stage1 + 0 * 256);
  lds_load16(xs1 + 32, stage1 + 1 * 256);
  lds_load16(xs2 + 32, stage1 + 2 * 256);
  lds_load16(xs3 + 32, stage1 + 3 * 256);
  SCHED_FENCE();
#pragma unroll
  for (int vn = 0; vn < 8; ++vn) breg[0][vn] = bptrw[vn * 64 + l];
#pragma unroll
  for (int vn = 0; vn < 8; ++vn) breg[1][vn] = bptrw[512 + vn * 64 + l];
  SCHED_FENCE();

  mmoe_step<0>(xs0, xs1, xs2, xs3, stage0, stage1, off00, off01, off10, off11, bptrw, l, breg, acc);
  mmoe_step<1>(xs0, xs1, xs2, xs3, stage0, stage1, off00, off01, off10, off11, bptrw, l, breg, acc);
  mmoe_step<2>(xs0, xs1, xs2, xs3, stage0, stage1, off00, off01, off10, off11, bptrw, l, breg, acc);
  mmoe_step<3>(xs0, xs1, xs2, xs3, stage0, stage1, off00, off01, off10, off11, bptrw, l, breg, acc);

  // ---- write partials into cmat (aliases staging region; own-wave region only) ----
  float* cmat = smem;
#pragma unroll
  for (int f = 0; f < 2; ++f)
#pragma unroll
    for (int nf = 0; nf < 4; ++nf)
#pragma unroll
      for (int r = 0; r < 4; ++r)
        cmat[w * 2048 + (f * 16 + (l >> 4) * 4 + r) * 64 + nf * 16 + (l & 15)] = acc[f][nf][r];
  __syncthreads();

  // ---- 8-way reduce + softmax-mix (threads 0..127: 32 rows x 4 tasks) ----
  if (tid < 128) {
    const int row = tid >> 2, t = tid & 3;
    float g[8] = {0.f, 0.f, 0.f, 0.f, 0.f, 0.f, 0.f, 0.f};
    float s[8] = {0.f, 0.f, 0.f, 0.f, 0.f, 0.f, 0.f, 0.f};
#pragma unroll
    for (int wv = 0; wv < 8; ++wv) {
      const float4 ga = *(const float4*)&cmat[wv * 2048 + row * 64 + t * 8];
      const float4 gb = *(const float4*)&cmat[wv * 2048 + row * 64 + t * 8 + 4];
      const float4 sa = *(const float4*)&cmat[wv * 2048 + row * 64 + 32 + t * 8];
      const float4 sb = *(const float4*)&cmat[wv * 2048 + row * 64 + 32 + t * 8 + 4];
      g[0] += ga.x; g[1] += ga.y; g[2] += ga.z; g[3] += ga.w;
      g[4] += gb.x; g[5] += gb.y; g[6] += gb.z; g[7] += gb.w;
      s[0] += sa.x; s[1] += sa.y; s[2] += sa.z; s[3] += sa.w;
      s[4] += sb.x; s[5] += sb.y; s[6] += sb.z; s[7] += sb.w;
    }
#pragma unroll
    for (int e = 0; e < 8; ++e) {
      g[e] += bgp[t * 8 + e];
      s[e] += cbias[t * 8 + e];
    }
    float m = g[0];
#pragma unroll
    for (int e = 1; e < 8; ++e) m = fmaxf(m, g[e]);
    float Z = 0.f, num = 0.f;
#pragma unroll
    for (int e = 0; e < 8; ++e) {
      float p2 = __expf(g[e] - m);
      Z += p2;
      num = fmaf(p2, s[e], num);
    }
    out[t * 16384 + b0g + row] = num / Z + btp[t];
  }
}

extern "C" void kernel_launch(void* const* d_in, const int* in_sizes, int n_in,
                              void* d_out, int out_size, void* d_ws, size_t ws_size,
                              hipStream_t stream) {
  const float* x  = (const float*)d_in[0];
  const float* We = (const float*)d_in[1];
  const float* be = (const float*)d_in[2];
  const float* Wg = (const float*)d_in[3];
  const float* bg = (const float*)d_in[4];
  const float* Wt = (const float*)d_in[5];
  const float* bt = (const float*)d_in[6];
  float* out = (float*)d_out;
  float* ws  = (float*)d_ws;   // needs 524416 bytes

  uint4* wf = (uint4*)((unsigned char*)d_ws + WFRAG_OFF_BYTES);

  hipLaunchKernelGGL(mmoe_precompute, dim3(2048), dim3(256), 0, stream, We, be, Wg, Wt, ws);
  hipLaunchKernelGGL(mmoe_swizzle,    dim3(64),   dim3(256), 0, stream, ws, wf);
  hipLaunchKernelGGL(mmoe_main,       dim3(512),  dim3(512), 0, stream, x, bg, bt, ws, out);
}